// Round 8
// baseline (3241.068 us; speedup 1.0000x reference)
//
#include <hip/hip_runtime.h>
#include <cstdint>
#include <cstddef>

// Problem dims (fixed by reference)
#define B_    64
#define T_    4096
#define H_    128
#define C1_   64
#define NCLS_ 40

#define LOG2E_    1.4426950408889634f
#define TWOLOG2E_ 2.8853900817779268f

typedef _Float16 half2_t __attribute__((ext_vector_type(2)));

__device__ __forceinline__ float fdot2(half2_t a, half2_t b, float c){
#if defined(__has_builtin) && __has_builtin(__builtin_amdgcn_fdot2)
  return __builtin_amdgcn_fdot2(a, b, c, false);   // v_dot2_f32_f16, full-rate
#else
  return fmaf((float)a.x, (float)b.x, fmaf((float)a.y, (float)b.y, c));
#endif
}
__device__ __forceinline__ half2_t bc2(unsigned int u){ return __builtin_bit_cast(half2_t, u); }
__device__ __forceinline__ half2_t pack2(float a, float b){
  half2_t r; r.x = (_Float16)a; r.y = (_Float16)b; return r;   // RTNE
}
// DPP row_ror:1 on a dword: dest[n] = src[(n-1) mod 16 within row]
__device__ __forceinline__ unsigned int rot1(unsigned int x){
  return (unsigned int)__builtin_amdgcn_update_dpp(0, (int)x, 0x121, 0xF, 0xF, true);
}
// x + x[lane^16] in all lanes (gfx950 v_permlane16_swap: t=u=x; swap; t+u)
__device__ __forceinline__ float red16(float x){
  int a = __float_as_int(x), b = a;
  asm volatile("v_permlane16_swap_b32 %0, %1" : "+v"(a), "+v"(b));
  return __int_as_float(a) + __int_as_float(b);
}
__device__ __forceinline__ float red32(float x){
  int a = __float_as_int(x), b = a;
  asm volatile("v_permlane32_swap_b32 %0, %1" : "+v"(a), "+v"(b));
  return __int_as_float(a) + __int_as_float(b);
}

// ---------------- kernel 1: 3x3 second-moment stats of x over B*T ----------------
__global__ __launch_bounds__(256) void stats_kernel(const float* __restrict__ x,
                                                    float* __restrict__ stats){
  int t = blockIdx.x * 256 + threadIdx.x;
  const float4* xv = (const float4*)x + (size_t)t * 3;
  float4 a = xv[0], b = xv[1], c = xv[2];
  float x0[4] = {a.x, a.w, b.z, c.y};
  float x1[4] = {a.y, b.x, b.w, c.z};
  float x2[4] = {a.z, b.y, c.x, c.w};
  float s[9] = {0,0,0,0,0,0,0,0,0};
  #pragma unroll
  for (int r=0;r<4;++r){
    s[0]+=x0[r]; s[1]+=x1[r]; s[2]+=x2[r];
    s[3]+=x0[r]*x0[r]; s[4]+=x0[r]*x1[r]; s[5]+=x0[r]*x2[r];
    s[6]+=x1[r]*x1[r]; s[7]+=x1[r]*x2[r]; s[8]+=x2[r]*x2[r];
  }
  __shared__ float red[9][256];
  #pragma unroll
  for (int j=0;j<9;++j) red[j][threadIdx.x] = s[j];
  __syncthreads();
  if (threadIdx.x < 9){
    float sum = 0.f;
    for (int i=0;i<256;++i) sum += red[threadIdx.x][i];
    atomicAdd(&stats[threadIdx.x], sum);
  }
}

// Fold conv + BN(train stats) + gamma/beta into per-channel affine. conv_b cancels.
__device__ __forceinline__ void chan_affine(int c, const float* __restrict__ conv_w,
    const float* __restrict__ bn_g, const float* __restrict__ bn_b,
    const float* __restrict__ stats,
    float& A0, float& A1, float& A2, float& Bc){
  const float Ninv = 1.0f / (float)(B_*T_);
  float m0=stats[0]*Ninv, m1=stats[1]*Ninv, m2=stats[2]*Ninv;
  float c00=stats[3]*Ninv-m0*m0, c01=stats[4]*Ninv-m0*m1, c02=stats[5]*Ninv-m0*m2;
  float c11=stats[6]*Ninv-m1*m1, c12=stats[7]*Ninv-m1*m2, c22=stats[8]*Ninv-m2*m2;
  float w0=conv_w[c*3+0], w1=conv_w[c*3+1], w2=conv_w[c*3+2];
  float var = w0*(w0*c00 + 2.f*(w1*c01 + w2*c02)) + w1*(w1*c11 + 2.f*w2*c12) + w2*w2*c22;
  float sc = bn_g[c] * rsqrtf(var + 1e-5f);
  A0 = w0*sc; A1 = w1*sc; A2 = w2*sc;
  Bc = bn_b[c] - (w0*m0 + w1*m1 + w2*m2)*sc;
}

// ---------------- kernel 2 (Tier A): y = relu(affine(x)) as f16 [B][T][64] ----------------
__global__ __launch_bounds__(256) void y_kernel(const float* __restrict__ x,
    const float* __restrict__ conv_w, const float* __restrict__ bn_g,
    const float* __restrict__ bn_b, const float* __restrict__ stats,
    _Float16* __restrict__ yg){
  __shared__ float4 coef[C1_];
  int tid = threadIdx.x;
  if (tid < C1_){
    float A0,A1,A2,Bc; chan_affine(tid, conv_w, bn_g, bn_b, stats, A0,A1,A2,Bc);
    coef[tid] = make_float4(A0,A1,A2,Bc);
  }
  __syncthreads();
  size_t idx = (size_t)blockIdx.x * 256 + tid;      // (b*T + t)
  const float* xp = x + idx*3;
  float x0 = xp[0], x1 = xp[1], x2 = xp[2];
  unsigned int ob[32];
  #pragma unroll
  for (int c=0; c<C1_; c+=2){
    float4 c0 = coef[c], c1 = coef[c+1];
    float v0 = fmaxf(fmaf(c0.x,x0, fmaf(c0.y,x1, fmaf(c0.z,x2, c0.w))), 0.f);
    float v1 = fmaxf(fmaf(c1.x,x0, fmaf(c1.y,x1, fmaf(c1.z,x2, c1.w))), 0.f);
    ob[c>>1] = __builtin_bit_cast(unsigned int, pack2(v0, v1));
  }
  uint4* dst = (uint4*)(yg + idx*C1_);
  #pragma unroll
  for (int i=0;i<8;++i) dst[i] = ((uint4*)ob)[i];
}

// ---------------- kernel 3: persistent per-batch LSTM, rotation-systolic ----------------
// 64 blocks x 512 threads (8 waves). Lane l, wave w: k = 16w + (l&15), row q = l>>4.
// h broadcast: ONE ds_read_b32/lane (lane l holds h-pair l = full h per wave); 16 iters of
// {4 dot2 + row_ror:1} cycle each lane through its row's 16 pairs (weights statically
// rotation-ordered per lane). Cross-row reduce via v_permlane16/32_swap (VALU): after,
// every lane holds all 4 gate sums for its k -> activations fully lane-local; c replicated
// x4; q==0 writes h (ds_write_b16). Gate exp2-scales folded into W/bias. Raw s_barrier +
// lgkmcnt(0) so the Tier-A y vmcnt prefetch stays in flight.
template<bool YG>
__global__ __launch_bounds__(512,2) void lstm_kernel(
    const _Float16* __restrict__ yg, const float* __restrict__ x,
    const float* __restrict__ conv_w, const float* __restrict__ bn_g,
    const float* __restrict__ bn_b, const float* __restrict__ stats,
    const float* __restrict__ w_ih, const float* __restrict__ b_ih,
    const float* __restrict__ b_hh, const float* __restrict__ w_hh,
    const float* __restrict__ h0, const float* __restrict__ c0,
    const float* __restrict__ out_w, const float* __restrict__ out_b,
    float* __restrict__ out){
  int b = blockIdx.x, t = threadIdx.x;
  int lane = t & 63, wv = t >> 6;
  int j = lane & 15, q = lane >> 4;
  int k = wv*16 + j;
  __shared__ __align__(16) _Float16 hbuf[2][H_];
  __shared__ __align__(16) _Float16 ybuf[4][C1_];   // Tier B mod-4 ring

  // h weights, rotation-ordered: slot r = pair q*16+((j-r)&15); prescaled by gate exp2-scale
  half2_t wh[4][16];
  half2_t wy[4][8];
  float bias[4];
  #pragma unroll
  for (int g=0; g<4; ++g){
    float sg = (g==2) ? TWOLOG2E_ : -LOG2E_;
    const float* wrow = w_hh + (size_t)(g*H_ + k)*H_;
    #pragma unroll
    for (int r=0;r<16;++r){
      int pidx = q*16 + ((j - r) & 15);
      wh[g][r] = pack2(sg*wrow[2*pidx], sg*wrow[2*pidx+1]);
    }
    const float* yrow = w_ih + (size_t)(g*H_ + k)*C1_ + q*16;
    #pragma unroll
    for (int i=0;i<8;++i)
      wy[g][i] = pack2(sg*yrow[2*i], sg*yrow[2*i+1]);
    bias[g] = sg * (b_ih[g*H_+k] + b_hh[g*H_+k]);
  }

  float cs = TWOLOG2E_ * c0[(size_t)b*H_ + k];      // scaled cell state (replicated x4 rows)
  if (q == 0) hbuf[0][k] = (_Float16)h0[(size_t)b*H_ + k];

  // ---- Tier B (in-kernel y) setup ----
  int yc = t >> 3; bool prod = ((t & 7) == 0);      // 64 producers
  float ya0=0, ya1=0, ya2=0, ya3=0;
  float xs0=0, xs1=0, xs2=0, xn0=0, xn1=0, xn2=0;
  const float* xb = x + (size_t)b*T_*3;
  if constexpr (!YG){
    chan_affine(yc, conv_w, bn_g, bn_b, stats, ya0, ya1, ya2, ya3);
    if (prod){
      float v0 = fmaf(ya0, xb[0], fmaf(ya1, xb[1], fmaf(ya2, xb[2], ya3)));
      float v1 = fmaf(ya0, xb[3], fmaf(ya1, xb[4], fmaf(ya2, xb[5], ya3)));
      ybuf[0][yc] = (_Float16)fmaxf(v0, 0.f);
      ybuf[1][yc] = (_Float16)fmaxf(v1, 0.f);
    }
    xs0 = xb[6];  xs1 = xb[7];  xs2 = xb[8];        // x[2]
    xn0 = xb[9];  xn1 = xb[10]; xn2 = xb[11];       // x[3]
  }
  // ---- Tier A y preload: window y[q*16 .. q*16+16) = 2 x uint4, double-buffered ----
  const _Float16* ygb = nullptr;
  uint4 ypf[2][2];
  if constexpr (YG){
    ygb = yg + (size_t)b*T_*C1_ + q*16;
    ypf[0][0] = *(const uint4*)(ygb);
    ypf[0][1] = *(const uint4*)(ygb + 8);
  }
  __syncthreads();

  #pragma unroll 2
  for (int step=0; step<T_; ++step){
    int p = step & 1;
    float acc[4] = {0.f,0.f,0.f,0.f};
    // ===== pre-barrier: y-dots (y known a step early) + next-y prefetch/production =====
    if constexpr (YG){
      uint4 yv0 = ypf[p][0], yv1 = ypf[p][1];
      half2_t y0_ = bc2(yv0.x), y1_ = bc2(yv0.y), y2_ = bc2(yv0.z), y3_ = bc2(yv0.w);
      half2_t y4_ = bc2(yv1.x), y5_ = bc2(yv1.y), y6_ = bc2(yv1.z), y7_ = bc2(yv1.w);
      #pragma unroll
      for (int g=0; g<4; ++g){
        acc[g] = fdot2(wy[g][0], y0_, acc[g]);
        acc[g] = fdot2(wy[g][1], y1_, acc[g]);
        acc[g] = fdot2(wy[g][2], y2_, acc[g]);
        acc[g] = fdot2(wy[g][3], y3_, acc[g]);
        acc[g] = fdot2(wy[g][4], y4_, acc[g]);
        acc[g] = fdot2(wy[g][5], y5_, acc[g]);
        acc[g] = fdot2(wy[g][6], y6_, acc[g]);
        acc[g] = fdot2(wy[g][7], y7_, acc[g]);
      }
      int tn = (step+1 < T_) ? step+1 : step;
      const _Float16* ypd = ygb + (size_t)tn*C1_;
      ypf[1-p][0] = *(const uint4*)(ypd);           // vmcnt domain; waits land next iter
      ypf[1-p][1] = *(const uint4*)(ypd + 8);
    } else {
      const _Float16* yb2 = &ybuf[step & 3][q*16];  // written >=2 barriers ago
      uint4 yv0 = *(const uint4*)(yb2);
      uint4 yv1 = *(const uint4*)(yb2 + 8);
      half2_t y0_ = bc2(yv0.x), y1_ = bc2(yv0.y), y2_ = bc2(yv0.z), y3_ = bc2(yv0.w);
      half2_t y4_ = bc2(yv1.x), y5_ = bc2(yv1.y), y6_ = bc2(yv1.z), y7_ = bc2(yv1.w);
      #pragma unroll
      for (int g=0; g<4; ++g){
        acc[g] = fdot2(wy[g][0], y0_, acc[g]);
        acc[g] = fdot2(wy[g][1], y1_, acc[g]);
        acc[g] = fdot2(wy[g][2], y2_, acc[g]);
        acc[g] = fdot2(wy[g][3], y3_, acc[g]);
        acc[g] = fdot2(wy[g][4], y4_, acc[g]);
        acc[g] = fdot2(wy[g][5], y5_, acc[g]);
        acc[g] = fdot2(wy[g][6], y6_, acc[g]);
        acc[g] = fdot2(wy[g][7], y7_, acc[g]);
      }
      float yn = fmaf(ya0, xs0, fmaf(ya1, xs1, fmaf(ya2, xs2, ya3)));
      if (prod) ybuf[(step+2) & 3][yc] = (_Float16)fmaxf(yn, 0.f);   // y[step+2]
      xs0=xn0; xs1=xn1; xs2=xn2;
      { int t4 = (step+4 < T_) ? step+4 : T_-1;
        const float* xp = xb + 3*t4; xn0=xp[0]; xn1=xp[1]; xn2=xp[2]; }
    }
    // ===== barrier (LDS drain only; vmcnt y-prefetch stays in flight) =====
    asm volatile("s_waitcnt lgkmcnt(0)" ::: "memory");
    __builtin_amdgcn_s_barrier();
    asm volatile("" ::: "memory");
    // ===== post-barrier: ONE b32 read = full h per wave; rotation-systolic dots =====
    unsigned int hp = ((const unsigned int*)hbuf[p])[lane];   // pair `lane`
    #pragma unroll
    for (int r=0;r<16;++r){
      half2_t hv = bc2(hp);
      acc[0] = fdot2(wh[0][r], hv, acc[0]);
      acc[1] = fdot2(wh[1][r], hv, acc[1]);
      acc[2] = fdot2(wh[2][r], hv, acc[2]);
      acc[3] = fdot2(wh[3][r], hv, acc[3]);
      if (r < 15) hp = rot1(hp);
    }
    // cross-row reduction (VALU permlane swaps): all lanes end with all 4 gate sums
    float g0 = red32(red16(acc[0])) + bias[0];
    float g1 = red32(red16(acc[1])) + bias[1];
    float g2 = red32(red16(acc[2])) + bias[2];
    float g3 = red32(red16(acc[3])) + bias[3];
    // lane-local activations (prescaled): sigmoid = rcp(1+exp2(v)); G-tanh = 1-2rcp(1+exp2(v))
    float e0 = __builtin_amdgcn_exp2f(g0);
    float e1 = __builtin_amdgcn_exp2f(g1);
    float e2 = __builtin_amdgcn_exp2f(g2);
    float e3 = __builtin_amdgcn_exp2f(g3);
    float Is = TWOLOG2E_ * __builtin_amdgcn_rcpf(1.f + e0);   // I pre-scaled by 2log2e
    float F  = __builtin_amdgcn_rcpf(1.f + e1);
    float G  = fmaf(-2.f, __builtin_amdgcn_rcpf(1.f + e2), 1.f);
    float O  = __builtin_amdgcn_rcpf(1.f + e3);
    cs = fmaf(F, cs, Is*G);                                   // scaled cell state
    float th = fmaf(-2.f, __builtin_amdgcn_rcpf(1.f + __builtin_amdgcn_exp2f(cs)), 1.f);
    float h = th * O;
    if (q == 0) hbuf[1-p][k] = (_Float16)h;
  }
  __syncthreads();
  // classifier epilogue on final h (T even -> buffer 0)
  if (t < NCLS_){
    float s = out_b[t];
    #pragma unroll 8
    for (int kk=0; kk<H_; ++kk)
      s = fmaf(out_w[t*H_ + kk], (float)hbuf[0][kk], s);
    out[(size_t)b*NCLS_ + t] = s;
  }
}

extern "C" void kernel_launch(void* const* d_in, const int* in_sizes, int n_in,
                              void* d_out, int out_size, void* d_ws, size_t ws_size,
                              hipStream_t stream){
  const float* x      = (const float*)d_in[0];
  const float* conv_w = (const float*)d_in[1];
  // d_in[2] = conv_b: cancels exactly inside BN(train stats) — unused
  const float* bn_g   = (const float*)d_in[3];
  const float* bn_b   = (const float*)d_in[4];
  const float* w_ih   = (const float*)d_in[5];
  const float* b_ih   = (const float*)d_in[6];
  const float* w_hh   = (const float*)d_in[7];
  const float* b_hh   = (const float*)d_in[8];
  const float* out_w  = (const float*)d_in[9];
  const float* out_b  = (const float*)d_in[10];
  const float* h0     = (const float*)d_in[11];
  const float* c0     = (const float*)d_in[12];
  float* out      = (float*)d_out;
  float* stats    = (float*)d_ws;
  _Float16* yg    = (_Float16*)((char*)d_ws + 4096);
  const size_t needA = 4096 + (size_t)B_*T_*C1_*sizeof(_Float16);   // ~33.6 MB

  hipMemsetAsync(d_ws, 0, 64, stream);
  stats_kernel<<<256, 256, 0, stream>>>(x, stats);
  if (ws_size >= needA){
    y_kernel<<<(B_*T_)/256, 256, 0, stream>>>(x, conv_w, bn_g, bn_b, stats, yg);
    lstm_kernel<true><<<B_, 512, 0, stream>>>(yg, x, conv_w, bn_g, bn_b, stats,
                                              w_ih, b_ih, b_hh, w_hh, h0, c0, out_w, out_b, out);
  } else {
    lstm_kernel<false><<<B_, 512, 0, stream>>>(yg, x, conv_w, bn_g, bn_b, stats,
                                               w_ih, b_ih, b_hh, w_hh, h0, c0, out_w, out_b, out);
  }
}